// Round 13
// baseline (247.992 us; speedup 1.0000x reference)
//
#include <hip/hip_runtime.h>
#include <hip/hip_bf16.h>

// Causal attention, B=4 S=2048 E=1024 D=1024, fp32 in/out.
// Round 21: fuse qk256 -> sc256 into ONE 400-block dispatch with a
// device-scope flag handshake (removes one ~11us dispatch boundary and
// overlaps qk tail with sc start):
//  - blocks 0..255  = qk tiles; after C-store: __syncthreads (drains vmcnt)
//    + thread0 __threadfence + agent-release store flag[swz]=1.
//  - blocks 256..399 = sc tiles; thread0 spins (agent-acquire + s_sleep) on
//    the 8 producer flags (Q: row-panel z*8+m cols 0..3; K: z*8+n cols 4..7),
//    then __syncthreads and run the tile.
//  - deadlock-free by counting: 144 consumers < 256 CUs -> >=112 producers
//    always resident; producers never wait. Flags zeroed by cast kernel.
// Everything else identical to r20 (measured 225.5us; 1-barrier lgkm-ladder
// 256^2 core, V+softmax at 4/CU, split-free paired-LPT pv).

typedef unsigned short u16;
typedef __attribute__((ext_vector_type(4))) u16   u16x4;
typedef __attribute__((ext_vector_type(8))) u16   u16x8;
typedef __attribute__((ext_vector_type(8))) short short8;
typedef __attribute__((ext_vector_type(4))) float f32x4;

__device__ inline u16 f2b(float v) {
    __hip_bfloat16 b = __float2bfloat16(v);
    return *reinterpret_cast<u16*>(&b);
}
__device__ inline float b2f(u16 v) {
    unsigned int u = ((unsigned int)v) << 16;
    return *reinterpret_cast<float*>(&u);
}

template <typename T> __device__ inline void store_elem(T* p, float v);
template <> __device__ inline void store_elem<float>(float* p, float v) { *p = v; }
template <> __device__ inline void store_elem<u16>(u16* p, float v)     { *p = f2b(v); }

// async global->LDS 16B per lane; LDS dest must be wave-uniform base + lane*16
__device__ inline void gload_lds16(const u16* g, u16* l) {
    __builtin_amdgcn_global_load_lds(
        (const __attribute__((address_space(1))) void*)g,
        (__attribute__((address_space(3))) void*)l, 16, 0, 0);
}

// inline-asm ds_read_b128: paired with explicit counted s_waitcnt lgkmcnt(N)
// + sched_barrier(0) (compiler hoists reg-only MFMA past asm waits).
__device__ __forceinline__ short8 dsr128(const u16* p) {
    short8 d;
    asm volatile("ds_read_b128 %0, %1"
        : "=v"(d)
        : "v"((unsigned)(unsigned long long)
              (const __attribute__((address_space(3))) u16*)p));
    return d;
}

// ---------------- merged fp32 -> bf16 cast: [x | wq | wk | wv] -------------
// grid-stride: 1408 blocks x 256 thr x 8 iters = 2883584 quads exact.
// Block 0 also zeroes the 256 qk->sc handshake flags (runs before gemm_qksc;
// the dispatch boundary guarantees visibility).
__global__ __launch_bounds__(256) void cast_all_kernel(
    const float* __restrict__ x,  const float* __restrict__ wq,
    const float* __restrict__ wk, const float* __restrict__ wv,
    u16* __restrict__ dst, unsigned int* __restrict__ flags) {
    if (blockIdx.x == 0 && threadIdx.x < 256) flags[threadIdx.x] = 0;
    int base = blockIdx.x * 256 + threadIdx.x;
#pragma unroll
    for (int k = 0; k < 8; ++k) {
        int q = k * 360448 + base;              // quad index
        const float* src;
        int sidx;
        if (q < 2097152) { src = x; sidx = q * 4; }
        else {
            int qq = q - 2097152;
            int w  = qq >> 18;                  // 262144 quads per weight
            sidx   = (qq & 262143) * 4;
            src    = (w == 0) ? wq : (w == 1) ? wk : wv;
        }
        float4 v = *(const float4*)(src + sidx);
        u16x4 o;
        o.x = f2b(v.x); o.y = f2b(v.y); o.z = f2b(v.z); o.w = f2b(v.w);
        *(u16x4*)(dst + q * 4) = o;
    }
}

// ---------------- 256x256 GEMM core (K=1024, C = A * B^T) ------------------
// r20 1-barrier counted-lgkm ladder. lds: 2*2*16384 u16 (128 KiB).
__device__ __forceinline__ void gemm256_core(
    u16* __restrict__ lds,
    const u16* __restrict__ Ab, int lda,
    const u16* __restrict__ Bb, int ldb,
    u16* __restrict__ Cb, int ldc,
    int m0, int n0)
{
    const int tid  = threadIdx.x;
    const int lane = tid & 63;
    const int wave = tid >> 6;
    const int quad = lane >> 4;
    const int r16  = lane & 15;
    const int wm   = wave >> 2;
    const int wn   = wave & 3;

    int gA[2][2], gB[2][2], lA[2][2], lB[2][2];
    {
        const int cswz = ((lane & 3) * 8) ^ (((lane >> 5) & 1) << 4);
        const int rsub = lane >> 2;
#pragma unroll
        for (int u = 0; u < 2; ++u)
#pragma unroll
            for (int j = 0; j < 2; ++j) {
                int s   = j * 8 + wave;
                int sh  = s >> 1, cg2 = s & 1;
                int rgA = (sh & 3) + (sh >> 2) * 8 + u * 4;
                int rgB = sh + u * 8;
                int cl  = cg2 * 32 + cswz;
                gA[u][j] = (m0 + rgA * 16 + rsub) * lda + cl;
                gB[u][j] = (n0 + rgB * 16 + rsub) * ldb + cl;
                lA[u][j] = (rgA * 2 + cg2) * 512 + lane * 8;
                lB[u][j] = (rgB * 2 + cg2) * 512 + lane * 8;
            }
    }

#define STAGE_A(BUF, U, KK) do { \
        gload_lds16(Ab + gA[U][0] + (KK), lds + (BUF)*32768 + lA[U][0]); \
        gload_lds16(Ab + gA[U][1] + (KK), lds + (BUF)*32768 + lA[U][1]); } while (0)
#define STAGE_B(BUF, U, KK) do { \
        gload_lds16(Bb + gB[U][0] + (KK), lds + (BUF)*32768 + 16384 + lB[U][0]); \
        gload_lds16(Bb + gB[U][1] + (KK), lds + (BUF)*32768 + 16384 + lB[U][1]); } while (0)

    const int cswr = (quad * 8) ^ ((r16 >> 3) << 4);
    const int rdA0 = wm * 16 * 512 + r16 * 32 + cswr;
    const int rdB0 = wn * 8  * 512 + r16 * 32 + cswr;

    f32x4 acc[8][4] = {};

    // prologue: stage tile0 -> buf0 only (1-ahead pipeline)
    STAGE_B(0, 0, 0); STAGE_B(0, 1, 0); STAGE_A(0, 0, 0); STAGE_A(0, 1, 0);
    asm volatile("s_waitcnt vmcnt(0)" ::: "memory");
    __builtin_amdgcn_s_barrier();

    for (int t = 0; t < 16; ++t) {
        const int  buf = t & 1;
        const bool pf  = (t < 15);
        const int  kk1 = t * 64 + 64;          // K offset of tile t+1
        const u16* Al  = lds + buf * 32768;
        const u16* Bl  = lds + buf * 32768 + 16384;
        short8 bfr[4][2], a01[2][2], a23[2][2], a45[2][2], a67[2][2];

        // stage tile t+1 into the OPPOSITE buffer (drained by end-of-iter
        // vmcnt(0); WAR-safe: buf^1's readers retired before last barrier).
        if (pf) {
            STAGE_B(buf ^ 1, 0, kk1); STAGE_B(buf ^ 1, 1, kk1);
            STAGE_A(buf ^ 1, 0, kk1); STAGE_A(buf ^ 1, 1, kk1);
        }
        __builtin_amdgcn_sched_barrier(0);

        // burst 1: B(8) + a01(4) + a23(4) = 16 reads in flight
#pragma unroll
        for (int nf = 0; nf < 4; ++nf)
#pragma unroll
            for (int ks = 0; ks < 2; ++ks)
                bfr[nf][ks] = dsr128(&Bl[rdB0 + (nf * 2 + ks) * 512]);
#pragma unroll
        for (int mf = 0; mf < 2; ++mf)
#pragma unroll
            for (int ks = 0; ks < 2; ++ks)
                a01[mf][ks] = dsr128(&Al[rdA0 + (mf * 2 + ks) * 512]);
#pragma unroll
        for (int mf = 0; mf < 2; ++mf)
#pragma unroll
            for (int ks = 0; ks < 2; ++ks)
                a23[mf][ks] = dsr128(&Al[rdA0 + ((mf + 2) * 2 + ks) * 512]);

        // group 0: wait oldest 12 (B + a01); a23 drains under MFMA
        asm volatile("s_waitcnt lgkmcnt(4)" ::: "memory");
        __builtin_amdgcn_sched_barrier(0);
        __builtin_amdgcn_s_setprio(1);
#pragma unroll
        for (int mf = 0; mf < 2; ++mf)
#pragma unroll
            for (int nf = 0; nf < 4; ++nf)
#pragma unroll
                for (int ks = 0; ks < 2; ++ks)
                    acc[mf][nf] = __builtin_amdgcn_mfma_f32_16x16x32_bf16(
                        a01[mf][ks], bfr[nf][ks], acc[mf][nf], 0, 0, 0);
        __builtin_amdgcn_s_setprio(0);

#pragma unroll
        for (int mf = 0; mf < 2; ++mf)
#pragma unroll
            for (int ks = 0; ks < 2; ++ks)
                a45[mf][ks] = dsr128(&Al[rdA0 + ((mf + 4) * 2 + ks) * 512]);

        // group 1: wait a23; a45 drains under MFMA
        asm volatile("s_waitcnt lgkmcnt(4)" ::: "memory");
        __builtin_amdgcn_sched_barrier(0);
        __builtin_amdgcn_s_setprio(1);
#pragma unroll
        for (int mf = 0; mf < 2; ++mf)
#pragma unroll
            for (int nf = 0; nf < 4; ++nf)
#pragma unroll
                for (int ks = 0; ks < 2; ++ks)
                    acc[mf + 2][nf] = __builtin_amdgcn_mfma_f32_16x16x32_bf16(
                        a23[mf][ks], bfr[nf][ks], acc[mf + 2][nf], 0, 0, 0);
        __builtin_amdgcn_s_setprio(0);

#pragma unroll
        for (int mf = 0; mf < 2; ++mf)
#pragma unroll
            for (int ks = 0; ks < 2; ++ks)
                a67[mf][ks] = dsr128(&Al[rdA0 + ((mf + 6) * 2 + ks) * 512]);

        // group 2: wait a45; a67 drains under MFMA
        asm volatile("s_waitcnt lgkmcnt(4)" ::: "memory");
        __builtin_amdgcn_sched_barrier(0);
        __builtin_amdgcn_s_setprio(1);
#pragma unroll
        for (int mf = 0; mf < 2; ++mf)
#pragma unroll
            for (int nf = 0; nf < 4; ++nf)
#pragma unroll
                for (int ks = 0; ks < 2; ++ks)
                    acc[mf + 4][nf] = __builtin_amdgcn_mfma_f32_16x16x32_bf16(
                        a45[mf][ks], bfr[nf][ks], acc[mf + 4][nf], 0, 0, 0);
        __builtin_amdgcn_s_setprio(0);

        // group 3: drain a67
        asm volatile("s_waitcnt lgkmcnt(0)" ::: "memory");
        __builtin_amdgcn_sched_barrier(0);
        __builtin_amdgcn_s_setprio(1);
#pragma unroll
        for (int mf = 0; mf < 2; ++mf)
#pragma unroll
            for (int nf = 0; nf < 4; ++nf)
#pragma unroll
                for (int ks = 0; ks < 2; ++ks)
                    acc[mf + 6][nf] = __builtin_amdgcn_mfma_f32_16x16x32_bf16(
                        a67[mf][ks], bfr[nf][ks], acc[mf + 6][nf], 0, 0, 0);
        __builtin_amdgcn_s_setprio(0);

        // tile t+1 fully landed; single barrier closes the tile.
        if (pf) asm volatile("s_waitcnt vmcnt(0)" ::: "memory");
        __builtin_amdgcn_s_barrier();
    }
#undef STAGE_A
#undef STAGE_B

#pragma unroll
    for (int mf = 0; mf < 8; ++mf) {
        int m = m0 + wm * 128 + mf * 16 + quad * 4;
#pragma unroll
        for (int nf = 0; nf < 4; ++nf) {
            int n = n0 + wn * 64 + nf * 16 + r16;
#pragma unroll
            for (int r = 0; r < 4; ++r)
                Cb[(m + r) * ldc + n] = f2b(acc[mf][nf][r]);
        }
    }
}

// ================= fused qk -> sc dispatch (flag handshake) ================
// blocks 0..255: qk = xb[8192,1024] x wb[0:2048]^T (XCD-swizzled, 1/CU).
// blocks 256..399: sc tiles; wait on the 8 producer flags, then compute.
__global__ __launch_bounds__(512) void gemm_qksc(
    const u16* __restrict__ xb, const u16* __restrict__ wb,
    u16* __restrict__ qk, u16* __restrict__ sc,
    unsigned int* __restrict__ flags)
{
    __shared__ __align__(16) u16 lds[2 * 2 * 16384];
    int flat = blockIdx.x;                     // 0..399
    if (flat < 256) {
        int swz = (flat & 7) * 32 + (flat >> 3);   // bijective XCD swizzle
        int m0  = (swz >> 3) * 256;
        int n0  = (swz & 7) * 256;
        gemm256_core(lds, xb, 1024, wb, 1024, qk, 2048, m0, n0);
        // release: all threads' C-stores drained (syncthreads emits
        // vmcnt(0)), then agent-scope fence + flag store.
        __syncthreads();
        if (threadIdx.x == 0) {
            __threadfence();
            __hip_atomic_store(&flags[swz], 1u, __ATOMIC_RELEASE,
                               __HIP_MEMORY_SCOPE_AGENT);
        }
    } else {
        int f   = flat - 256;                  // 0..143
        int swz = (f & 7) * 18 + (f >> 3);     // each XCD: 18 consecutive
        int z   = swz / 36;
        int t   = swz - z * 36;                // 0..35 lower-tri (8x8)
        float ff = sqrtf(8.0f * t + 1.0f);
        int m = (int)((ff - 1.0f) * 0.5f);
        while ((m + 1) * (m + 2) / 2 <= t) m++;
        while (m * (m + 1) / 2 > t) m--;
        int n = t - m * (m + 1) / 2;
        // acquire: Q panels = row-panel z*8+m, col-panels 0..3;
        //          K panels = row-panel z*8+n, col-panels 4..7.
        if (threadIdx.x == 0) {
            int rq = (z * 8 + m) * 8, rk = (z * 8 + n) * 8;
#pragma unroll
            for (int j = 0; j < 4; ++j) {
                while (__hip_atomic_load(&flags[rq + j], __ATOMIC_ACQUIRE,
                                         __HIP_MEMORY_SCOPE_AGENT) == 0u)
                    __builtin_amdgcn_s_sleep(8);
                while (__hip_atomic_load(&flags[rk + 4 + j], __ATOMIC_ACQUIRE,
                                         __HIP_MEMORY_SCOPE_AGENT) == 0u)
                    __builtin_amdgcn_s_sleep(8);
            }
        }
        __syncthreads();
        const u16* Ab = qk + (long long)z * 2048 * 2048;
        gemm256_core(lds, Ab, 2048, Ab + 1024, 2048,
                     sc + (long long)z * 2048 * 2048, 2048, m * 256, n * 256);
    }
}

// ---------------- BT-GEMM core 128^2 (V / pv) -------------------------------
#define MT 128
#define NT 128
#define BKH 32
#define HSZ (MT * BKH)   // elems per half buffer = 4096

template <int TRANS, typename OutT>
__device__ __forceinline__ void gemm_core(
    u16* __restrict__ As, u16* __restrict__ Bs,
    const u16* __restrict__ Ab, int lda,
    const u16* __restrict__ Bb, int ldb,
    OutT* __restrict__ Cb, int ldc,
    int m0, int n0, int kbeg, int kend)
{
    const int tid  = threadIdx.x;
    const int lane = tid & 63;
    const int wave = tid >> 6;
    const int quad = lane >> 4;
    const int r16  = lane & 15;
    const int mw   = (wave >> 1) * 64;
    const int nw   = (wave & 1) * 64;

    const int c0 = tid, c1 = tid + 256;
    const int r0 = c0 >> 2, k0 = (c0 & 3) * 8;
    const int r1 = c1 >> 2, k1 = (c1 & 3) * 8;
    const int oa0 = (m0 + r0) * lda + k0;
    const int oa1 = (m0 + r1) * lda + k1;
    const int ob0 = (n0 + r0) * ldb + k0;
    const int ob1 = (n0 + r1) * ldb + k1;

    f32x4 acc[4][4] = {};

    for (int kk = kbeg; kk < kend; kk += 2 * BKH) {
        __syncthreads();
        gload_lds16(Ab + (kk + oa0),        &As[c0 * 8]);
        gload_lds16(Ab + (kk + oa1),        &As[c1 * 8]);
        gload_lds16(Ab + (kk + BKH + oa0),  &As[HSZ + c0 * 8]);
        gload_lds16(Ab + (kk + BKH + oa1),  &As[HSZ + c1 * 8]);
        gload_lds16(Bb + (kk + ob0),        &Bs[c0 * 8]);
        gload_lds16(Bb + (kk + ob1),        &Bs[c1 * 8]);
        gload_lds16(Bb + (kk + BKH + ob0),  &Bs[HSZ + c0 * 8]);
        gload_lds16(Bb + (kk + BKH + ob1),  &Bs[HSZ + c1 * 8]);
        __syncthreads();

#pragma unroll
        for (int h = 0; h < 2; h++) {
            short8 af[4], bf[4];
#pragma unroll
            for (int i = 0; i < 4; i++)
                af[i] = *(const short8*)&As[h * HSZ + (mw + i * 16 + r16) * BKH + quad * 8];
#pragma unroll
            for (int j = 0; j < 4; j++)
                bf[j] = *(const short8*)&Bs[h * HSZ + (nw + j * 16 + r16) * BKH + quad * 8];
#pragma unroll
            for (int i = 0; i < 4; i++)
#pragma unroll
                for (int j = 0; j < 4; j++)
                    acc[i][j] = __builtin_amdgcn_mfma_f32_16x16x32_bf16(af[i], bf[j], acc[i][j], 0, 0, 0);
        }
    }

    if (TRANS == 0) {
#pragma unroll
        for (int i = 0; i < 4; i++)
#pragma unroll
            for (int j = 0; j < 4; j++)
#pragma unroll
                for (int r = 0; r < 4; r++) {
                    int m = m0 + mw + i * 16 + quad * 4 + r;
                    int n = n0 + nw + j * 16 + r16;
                    store_elem(&Cb[(long long)m * ldc + n], acc[i][j][r]);
                }
    } else {
#pragma unroll
        for (int i = 0; i < 4; i++)
#pragma unroll
            for (int j = 0; j < 4; j++) {
                int mbase = m0 + mw + i * 16 + quad * 4;
                int d     = n0 + nw + j * 16 + r16;
                int b     = mbase >> 11;
                int s     = mbase & 2047;
                u16x4 o;
#pragma unroll
                for (int r = 0; r < 4; r++) o[r] = f2b(acc[i][j][r]);
                *(u16x4*)((u16*)Cb + (((b << 10) + d) * 2048 + s)) = o;
            }
    }
}

// ---------------- single-pass causal softmax row ----------------------------
__device__ __forceinline__ void softmax_row(const u16* __restrict__ sc,
                                            u16* __restrict__ P, int row,
                                            float* __restrict__ red) {
    const int S = 2048;
    int i   = row & (S - 1);
    int n   = i + 1;
    int kendr = (i & ~127) + 128;
    const u16* srow = sc + (long long)row * S;
    u16*       prow = P  + (long long)row * S;

    int j0 = threadIdx.x * 8;
    u16x8 raw = {};
    if (j0 <= i) raw = *(const u16x8*)(srow + j0);
    float v[8];
#pragma unroll
    for (int e = 0; e < 8; e++) v[e] = (j0 + e < n) ? b2f(raw[e]) : -1e30f;

    float lmax = v[0];
#pragma unroll
    for (int e = 1; e < 8; e++) lmax = fmaxf(lmax, v[e]);
    for (int o = 32; o > 0; o >>= 1) lmax = fmaxf(lmax, __shfl_xor(lmax, o, 64));
    int wid = threadIdx.x >> 6;
    if ((threadIdx.x & 63) == 0) red[wid] = lmax;
    __syncthreads();
    float Mx = fmaxf(fmaxf(red[0], red[1]), fmaxf(red[2], red[3]));

    // exp((s-Mx)/32) = exp2((s-Mx) * (1/(32 ln2)))
    const float C = 0.045112384f;
    float ev[8];
    float lsum = 0.f;
#pragma unroll
    for (int e = 0; e < 8; e++) {
        ev[e] = (j0 + e < n) ? exp2f((v[e] - Mx) * C) : 0.f;
        lsum += ev[e];
    }
    for (int o = 32; o > 0; o >>= 1) lsum += __shfl_xor(lsum, o, 64);
    if ((threadIdx.x & 63) == 0) red[4 + wid] = lsum;
    __syncthreads();
    float inv = 1.0f / (red[4] + red[5] + red[6] + red[7]);

    if (j0 < kendr) {
        u16x8 o8;
#pragma unroll
        for (int e = 0; e < 8; e++) o8[e] = f2b(ev[e] * inv);
        *(u16x8*)(prow + j0) = o8;
    }
}

// V projection (512 blocks, first so they're resident early) + paired-row
// softmax (4096 blocks). V depends only on cast; softmax only on sc.
__global__ __launch_bounds__(256, 4) void v_softmax(
    const u16* __restrict__ xb, const u16* __restrict__ wb,
    u16* __restrict__ vt,
    const u16* __restrict__ sc, u16* __restrict__ P)
{
    __shared__ __align__(16) u16 As[2 * HSZ];
    __shared__ __align__(16) u16 Bs[2 * HSZ];
    int bid = blockIdx.x;
    if (bid < 512) {
        int vb = (bid & 7) * 64 + (bid >> 3);   // XCD-chunked
        int m0 = (vb >> 3) * MT;
        int n0 = (vb & 7) * NT;
        gemm_core<1, u16>(As, Bs, xb, 1024, wb + 2048 * 1024, 1024, vt, 2048,
                          m0, n0, 0, 1024);
    } else {
        float* red = (float*)As;
        int sid = bid - 512;                    // 0..4095
        int z = sid >> 10, i = sid & 1023;
        softmax_row(sc, P, z * 2048 + (2047 - i), red);
        __syncthreads();
        softmax_row(sc, P, z * 2048 + i, red);
    }
}

// ---------------- PV: split-free triangular tiles, paired LPT order --------
// Each block computes one 128x128 out-tile with its FULL causal K =
// (m+1)*128 and stores once. Block c and c+256 land on the same CU and sum
// to a constant 17 K-units; all 512 blocks co-resident.
__global__ __launch_bounds__(256, 4) void gemm_pv(
    const u16* __restrict__ P, const u16* __restrict__ vt,
    float* __restrict__ out)
{
    __shared__ __align__(16) u16 As[2 * HSZ];
    __shared__ __align__(16) u16 Bs[2 * HSZ];
    const int bid = blockIdx.x;              // 0..511
    const int m  = (bid < 256) ? (15 - (bid >> 5)) : ((bid - 256) >> 5);
    const int nz = bid & 31;
    const int n  = nz & 7;
    const int z  = nz >> 3;
    const int m0 = m * MT;

    gemm_core<0, float>(As, Bs,
        P  + (long long)z * 2048 * 2048, 2048,
        vt + (long long)z * 1024 * 2048, 2048,
        out + (long long)z * 2097152, 1024,
        m0, n * NT, 0, m0 + MT);
}

extern "C" void kernel_launch(void* const* d_in, const int* in_sizes, int n_in,
                              void* d_out, int out_size, void* d_ws, size_t ws_size,
                              hipStream_t stream) {
    const float* x  = (const float*)d_in[0];
    const float* wq = (const float*)d_in[1];
    const float* wk = (const float*)d_in[2];
    const float* wv = (const float*)d_in[3];
    float* out = (float*)d_out;

    char* ws = (char*)d_ws;
    // layout: xb 16M | wb 6M | qk 32M | sc 32M | P 32M | vt 16M | flags 1K
    u16* xb = (u16*)(ws);
    u16* wb = (u16*)(ws + 16777216LL);
    u16* qk = (u16*)(ws + 23068672LL);
    u16* sc = (u16*)(ws + 56623104LL);
    u16* P  = (u16*)(ws + 90177536LL);
    u16* vt = (u16*)(ws + 123731968LL);
    unsigned int* flags = (unsigned int*)(ws + 140509184LL);

    // 1. casts (x + 3 weights) + flag zeroing, grid-stride
    cast_all_kernel<<<1408, 256, 0, stream>>>(x, wq, wk, wv, xb, flags);

    // 2+3. fused QK projection -> scores via device-scope flag handshake
    gemm_qksc<<<400, 512, 0, stream>>>(xb, wb, qk, sc, flags);

    // 4. V projection + causal softmax, one dispatch (4 blocks/CU residency)
    v_softmax<<<4608, 256, 0, stream>>>(xb, wb, vt, sc, P);

    // 5. PV: split-free triangular tiles, paired LPT ordering
    gemm_pv<<<512, 256, 0, stream>>>(P, vt, out);
}

// Round 14
// 223.358 us; speedup vs baseline: 1.1103x; 1.1103x over previous
//
#include <hip/hip_runtime.h>
#include <hip/hip_bf16.h>

// Causal attention, B=4 S=2048 E=1024 D=1024, fp32 in/out.
// Round 22: revert r21's flag-handshake fusion (104.8us fused vs 88us for
// qk+sc+boundary: at 1 block/CU the 256 producers fill ALL CUs first, so
// consumers cannot overlap -- they just form a ragged second round; lesson:
// on gfx950, inter-kernel deps are cheapest at dispatch boundaries).
// This is the measured-best r20 configuration verbatim (225.5us):
//  - 256^2 core with 1-barrier-per-tile counted-lgkm ladder (port-bound fix),
//  - chain: cast(1408 grid-stride) -> qk256(256, 1/CU) -> sc256(144) ->
//    V+softmax(4608, 4/CU) -> pv(512, split-free paired LPT).

typedef unsigned short u16;
typedef __attribute__((ext_vector_type(4))) u16   u16x4;
typedef __attribute__((ext_vector_type(8))) u16   u16x8;
typedef __attribute__((ext_vector_type(8))) short short8;
typedef __attribute__((ext_vector_type(4))) float f32x4;

__device__ inline u16 f2b(float v) {
    __hip_bfloat16 b = __float2bfloat16(v);
    return *reinterpret_cast<u16*>(&b);
}
__device__ inline float b2f(u16 v) {
    unsigned int u = ((unsigned int)v) << 16;
    return *reinterpret_cast<float*>(&u);
}

template <typename T> __device__ inline void store_elem(T* p, float v);
template <> __device__ inline void store_elem<float>(float* p, float v) { *p = v; }
template <> __device__ inline void store_elem<u16>(u16* p, float v)     { *p = f2b(v); }

// async global->LDS 16B per lane; LDS dest must be wave-uniform base + lane*16
__device__ inline void gload_lds16(const u16* g, u16* l) {
    __builtin_amdgcn_global_load_lds(
        (const __attribute__((address_space(1))) void*)g,
        (__attribute__((address_space(3))) void*)l, 16, 0, 0);
}

// inline-asm ds_read_b128: paired with explicit counted s_waitcnt lgkmcnt(N)
// + sched_barrier(0) (compiler hoists reg-only MFMA past asm waits).
__device__ __forceinline__ short8 dsr128(const u16* p) {
    short8 d;
    asm volatile("ds_read_b128 %0, %1"
        : "=v"(d)
        : "v"((unsigned)(unsigned long long)
              (const __attribute__((address_space(3))) u16*)p));
    return d;
}

// ---------------- merged fp32 -> bf16 cast: [x | wq | wk | wv] -------------
// grid-stride: 1408 blocks x 256 thr x 8 iters = 2883584 quads exact.
__global__ __launch_bounds__(256) void cast_all_kernel(
    const float* __restrict__ x,  const float* __restrict__ wq,
    const float* __restrict__ wk, const float* __restrict__ wv,
    u16* __restrict__ dst) {
    int base = blockIdx.x * 256 + threadIdx.x;
#pragma unroll
    for (int k = 0; k < 8; ++k) {
        int q = k * 360448 + base;              // quad index
        const float* src;
        int sidx;
        if (q < 2097152) { src = x; sidx = q * 4; }
        else {
            int qq = q - 2097152;
            int w  = qq >> 18;                  // 262144 quads per weight
            sidx   = (qq & 262143) * 4;
            src    = (w == 0) ? wq : (w == 1) ? wk : wv;
        }
        float4 v = *(const float4*)(src + sidx);
        u16x4 o;
        o.x = f2b(v.x); o.y = f2b(v.y); o.z = f2b(v.z); o.w = f2b(v.w);
        *(u16x4*)(dst + q * 4) = o;
    }
}

// ---------------- 256x256 GEMM core (K=1024, C = A * B^T) ------------------
// 1-barrier-per-tile counted-lgkm ladder. lds: 2*2*16384 u16 (128 KiB).
__device__ __forceinline__ void gemm256_core(
    u16* __restrict__ lds,
    const u16* __restrict__ Ab, int lda,
    const u16* __restrict__ Bb, int ldb,
    u16* __restrict__ Cb, int ldc,
    int m0, int n0)
{
    const int tid  = threadIdx.x;
    const int lane = tid & 63;
    const int wave = tid >> 6;
    const int quad = lane >> 4;
    const int r16  = lane & 15;
    const int wm   = wave >> 2;
    const int wn   = wave & 3;

    int gA[2][2], gB[2][2], lA[2][2], lB[2][2];
    {
        const int cswz = ((lane & 3) * 8) ^ (((lane >> 5) & 1) << 4);
        const int rsub = lane >> 2;
#pragma unroll
        for (int u = 0; u < 2; ++u)
#pragma unroll
            for (int j = 0; j < 2; ++j) {
                int s   = j * 8 + wave;
                int sh  = s >> 1, cg2 = s & 1;
                int rgA = (sh & 3) + (sh >> 2) * 8 + u * 4;
                int rgB = sh + u * 8;
                int cl  = cg2 * 32 + cswz;
                gA[u][j] = (m0 + rgA * 16 + rsub) * lda + cl;
                gB[u][j] = (n0 + rgB * 16 + rsub) * ldb + cl;
                lA[u][j] = (rgA * 2 + cg2) * 512 + lane * 8;
                lB[u][j] = (rgB * 2 + cg2) * 512 + lane * 8;
            }
    }

#define STAGE_A(BUF, U, KK) do { \
        gload_lds16(Ab + gA[U][0] + (KK), lds + (BUF)*32768 + lA[U][0]); \
        gload_lds16(Ab + gA[U][1] + (KK), lds + (BUF)*32768 + lA[U][1]); } while (0)
#define STAGE_B(BUF, U, KK) do { \
        gload_lds16(Bb + gB[U][0] + (KK), lds + (BUF)*32768 + 16384 + lB[U][0]); \
        gload_lds16(Bb + gB[U][1] + (KK), lds + (BUF)*32768 + 16384 + lB[U][1]); } while (0)

    const int cswr = (quad * 8) ^ ((r16 >> 3) << 4);
    const int rdA0 = wm * 16 * 512 + r16 * 32 + cswr;
    const int rdB0 = wn * 8  * 512 + r16 * 32 + cswr;

    f32x4 acc[8][4] = {};

    // prologue: stage tile0 -> buf0 only (1-ahead pipeline)
    STAGE_B(0, 0, 0); STAGE_B(0, 1, 0); STAGE_A(0, 0, 0); STAGE_A(0, 1, 0);
    asm volatile("s_waitcnt vmcnt(0)" ::: "memory");
    __builtin_amdgcn_s_barrier();

    for (int t = 0; t < 16; ++t) {
        const int  buf = t & 1;
        const bool pf  = (t < 15);
        const int  kk1 = t * 64 + 64;          // K offset of tile t+1
        const u16* Al  = lds + buf * 32768;
        const u16* Bl  = lds + buf * 32768 + 16384;
        short8 bfr[4][2], a01[2][2], a23[2][2], a45[2][2], a67[2][2];

        // stage tile t+1 into the OPPOSITE buffer (drained by end-of-iter
        // vmcnt(0); WAR-safe: buf^1's readers retired before last barrier).
        if (pf) {
            STAGE_B(buf ^ 1, 0, kk1); STAGE_B(buf ^ 1, 1, kk1);
            STAGE_A(buf ^ 1, 0, kk1); STAGE_A(buf ^ 1, 1, kk1);
        }
        __builtin_amdgcn_sched_barrier(0);

        // burst 1: B(8) + a01(4) + a23(4) = 16 reads in flight
#pragma unroll
        for (int nf = 0; nf < 4; ++nf)
#pragma unroll
            for (int ks = 0; ks < 2; ++ks)
                bfr[nf][ks] = dsr128(&Bl[rdB0 + (nf * 2 + ks) * 512]);
#pragma unroll
        for (int mf = 0; mf < 2; ++mf)
#pragma unroll
            for (int ks = 0; ks < 2; ++ks)
                a01[mf][ks] = dsr128(&Al[rdA0 + (mf * 2 + ks) * 512]);
#pragma unroll
        for (int mf = 0; mf < 2; ++mf)
#pragma unroll
            for (int ks = 0; ks < 2; ++ks)
                a23[mf][ks] = dsr128(&Al[rdA0 + ((mf + 2) * 2 + ks) * 512]);

        // group 0: wait oldest 12 (B + a01); a23 drains under MFMA
        asm volatile("s_waitcnt lgkmcnt(4)" ::: "memory");
        __builtin_amdgcn_sched_barrier(0);
        __builtin_amdgcn_s_setprio(1);
#pragma unroll
        for (int mf = 0; mf < 2; ++mf)
#pragma unroll
            for (int nf = 0; nf < 4; ++nf)
#pragma unroll
                for (int ks = 0; ks < 2; ++ks)
                    acc[mf][nf] = __builtin_amdgcn_mfma_f32_16x16x32_bf16(
                        a01[mf][ks], bfr[nf][ks], acc[mf][nf], 0, 0, 0);
        __builtin_amdgcn_s_setprio(0);

#pragma unroll
        for (int mf = 0; mf < 2; ++mf)
#pragma unroll
            for (int ks = 0; ks < 2; ++ks)
                a45[mf][ks] = dsr128(&Al[rdA0 + ((mf + 4) * 2 + ks) * 512]);

        // group 1: wait a23; a45 drains under MFMA
        asm volatile("s_waitcnt lgkmcnt(4)" ::: "memory");
        __builtin_amdgcn_sched_barrier(0);
        __builtin_amdgcn_s_setprio(1);
#pragma unroll
        for (int mf = 0; mf < 2; ++mf)
#pragma unroll
            for (int nf = 0; nf < 4; ++nf)
#pragma unroll
                for (int ks = 0; ks < 2; ++ks)
                    acc[mf + 2][nf] = __builtin_amdgcn_mfma_f32_16x16x32_bf16(
                        a23[mf][ks], bfr[nf][ks], acc[mf + 2][nf], 0, 0, 0);
        __builtin_amdgcn_s_setprio(0);

#pragma unroll
        for (int mf = 0; mf < 2; ++mf)
#pragma unroll
            for (int ks = 0; ks < 2; ++ks)
                a67[mf][ks] = dsr128(&Al[rdA0 + ((mf + 6) * 2 + ks) * 512]);

        // group 2: wait a45; a67 drains under MFMA
        asm volatile("s_waitcnt lgkmcnt(4)" ::: "memory");
        __builtin_amdgcn_sched_barrier(0);
        __builtin_amdgcn_s_setprio(1);
#pragma unroll
        for (int mf = 0; mf < 2; ++mf)
#pragma unroll
            for (int nf = 0; nf < 4; ++nf)
#pragma unroll
                for (int ks = 0; ks < 2; ++ks)
                    acc[mf + 4][nf] = __builtin_amdgcn_mfma_f32_16x16x32_bf16(
                        a45[mf][ks], bfr[nf][ks], acc[mf + 4][nf], 0, 0, 0);
        __builtin_amdgcn_s_setprio(0);

        // group 3: drain a67
        asm volatile("s_waitcnt lgkmcnt(0)" ::: "memory");
        __builtin_amdgcn_sched_barrier(0);
        __builtin_amdgcn_s_setprio(1);
#pragma unroll
        for (int mf = 0; mf < 2; ++mf)
#pragma unroll
            for (int nf = 0; nf < 4; ++nf)
#pragma unroll
                for (int ks = 0; ks < 2; ++ks)
                    acc[mf + 6][nf] = __builtin_amdgcn_mfma_f32_16x16x32_bf16(
                        a67[mf][ks], bfr[nf][ks], acc[mf + 6][nf], 0, 0, 0);
        __builtin_amdgcn_s_setprio(0);

        // tile t+1 fully landed; single barrier closes the tile.
        if (pf) asm volatile("s_waitcnt vmcnt(0)" ::: "memory");
        __builtin_amdgcn_s_barrier();
    }
#undef STAGE_A
#undef STAGE_B

#pragma unroll
    for (int mf = 0; mf < 8; ++mf) {
        int m = m0 + wm * 128 + mf * 16 + quad * 4;
#pragma unroll
        for (int nf = 0; nf < 4; ++nf) {
            int n = n0 + wn * 64 + nf * 16 + r16;
#pragma unroll
            for (int r = 0; r < 4; ++r)
                Cb[(m + r) * ldc + n] = f2b(acc[mf][nf][r]);
        }
    }
}

// qk = xb[8192,1024] x wb[0:2048]^T; 256 blocks = 1/CU exactly.
__global__ __launch_bounds__(512) void gemm_qk256(
    const u16* __restrict__ xb, const u16* __restrict__ wb,
    u16* __restrict__ qk)
{
    __shared__ __align__(16) u16 lds[2 * 2 * 16384];
    int flat = blockIdx.x;                     // 0..255
    int swz  = (flat & 7) * 32 + (flat >> 3);  // bijective XCD swizzle
    int m0   = (swz >> 3) * 256;
    int n0   = (swz & 7) * 256;
    gemm256_core(lds, xb, 1024, wb, 1024, qk, 2048, m0, n0);
}

// scores: per batch 36 lower-tri 256^2 tiles (diag tiles full; upper garbage
// masked by softmax). 144 blocks = 8 XCD x 18.
__global__ __launch_bounds__(512) void gemm_sc256(
    const u16* __restrict__ qk, u16* __restrict__ sc)
{
    __shared__ __align__(16) u16 lds[2 * 2 * 16384];
    int flat = blockIdx.x;                     // 0..143
    int swz  = (flat & 7) * 18 + (flat >> 3);  // each XCD: 18 consecutive
    int z    = swz / 36;
    int t    = swz - z * 36;                   // 0..35 lower-tri (8x8)
    float ff = sqrtf(8.0f * t + 1.0f);
    int m = (int)((ff - 1.0f) * 0.5f);
    while ((m + 1) * (m + 2) / 2 <= t) m++;
    while (m * (m + 1) / 2 > t) m--;
    int n = t - m * (m + 1) / 2;
    const u16* Ab = qk + (long long)z * 2048 * 2048;
    gemm256_core(lds, Ab, 2048, Ab + 1024, 2048,
                 sc + (long long)z * 2048 * 2048, 2048, m * 256, n * 256);
}

// ---------------- BT-GEMM core 128^2 (V / pv) -------------------------------
#define MT 128
#define NT 128
#define BKH 32
#define HSZ (MT * BKH)   // elems per half buffer = 4096

template <int TRANS, typename OutT>
__device__ __forceinline__ void gemm_core(
    u16* __restrict__ As, u16* __restrict__ Bs,
    const u16* __restrict__ Ab, int lda,
    const u16* __restrict__ Bb, int ldb,
    OutT* __restrict__ Cb, int ldc,
    int m0, int n0, int kbeg, int kend)
{
    const int tid  = threadIdx.x;
    const int lane = tid & 63;
    const int wave = tid >> 6;
    const int quad = lane >> 4;
    const int r16  = lane & 15;
    const int mw   = (wave >> 1) * 64;
    const int nw   = (wave & 1) * 64;

    const int c0 = tid, c1 = tid + 256;
    const int r0 = c0 >> 2, k0 = (c0 & 3) * 8;
    const int r1 = c1 >> 2, k1 = (c1 & 3) * 8;
    const int oa0 = (m0 + r0) * lda + k0;
    const int oa1 = (m0 + r1) * lda + k1;
    const int ob0 = (n0 + r0) * ldb + k0;
    const int ob1 = (n0 + r1) * ldb + k1;

    f32x4 acc[4][4] = {};

    for (int kk = kbeg; kk < kend; kk += 2 * BKH) {
        __syncthreads();
        gload_lds16(Ab + (kk + oa0),        &As[c0 * 8]);
        gload_lds16(Ab + (kk + oa1),        &As[c1 * 8]);
        gload_lds16(Ab + (kk + BKH + oa0),  &As[HSZ + c0 * 8]);
        gload_lds16(Ab + (kk + BKH + oa1),  &As[HSZ + c1 * 8]);
        gload_lds16(Bb + (kk + ob0),        &Bs[c0 * 8]);
        gload_lds16(Bb + (kk + ob1),        &Bs[c1 * 8]);
        gload_lds16(Bb + (kk + BKH + ob0),  &Bs[HSZ + c0 * 8]);
        gload_lds16(Bb + (kk + BKH + ob1),  &Bs[HSZ + c1 * 8]);
        __syncthreads();

#pragma unroll
        for (int h = 0; h < 2; h++) {
            short8 af[4], bf[4];
#pragma unroll
            for (int i = 0; i < 4; i++)
                af[i] = *(const short8*)&As[h * HSZ + (mw + i * 16 + r16) * BKH + quad * 8];
#pragma unroll
            for (int j = 0; j < 4; j++)
                bf[j] = *(const short8*)&Bs[h * HSZ + (nw + j * 16 + r16) * BKH + quad * 8];
#pragma unroll
            for (int i = 0; i < 4; i++)
#pragma unroll
                for (int j = 0; j < 4; j++)
                    acc[i][j] = __builtin_amdgcn_mfma_f32_16x16x32_bf16(af[i], bf[j], acc[i][j], 0, 0, 0);
        }
    }

    if (TRANS == 0) {
#pragma unroll
        for (int i = 0; i < 4; i++)
#pragma unroll
            for (int j = 0; j < 4; j++)
#pragma unroll
                for (int r = 0; r < 4; r++) {
                    int m = m0 + mw + i * 16 + quad * 4 + r;
                    int n = n0 + nw + j * 16 + r16;
                    store_elem(&Cb[(long long)m * ldc + n], acc[i][j][r]);
                }
    } else {
#pragma unroll
        for (int i = 0; i < 4; i++)
#pragma unroll
            for (int j = 0; j < 4; j++) {
                int mbase = m0 + mw + i * 16 + quad * 4;
                int d     = n0 + nw + j * 16 + r16;
                int b     = mbase >> 11;
                int s     = mbase & 2047;
                u16x4 o;
#pragma unroll
                for (int r = 0; r < 4; r++) o[r] = f2b(acc[i][j][r]);
                *(u16x4*)((u16*)Cb + (((b << 10) + d) * 2048 + s)) = o;
            }
    }
}

// ---------------- single-pass causal softmax row ----------------------------
__device__ __forceinline__ void softmax_row(const u16* __restrict__ sc,
                                            u16* __restrict__ P, int row,
                                            float* __restrict__ red) {
    const int S = 2048;
    int i   = row & (S - 1);
    int n   = i + 1;
    int kendr = (i & ~127) + 128;
    const u16* srow = sc + (long long)row * S;
    u16*       prow = P  + (long long)row * S;

    int j0 = threadIdx.x * 8;
    u16x8 raw = {};
    if (j0 <= i) raw = *(const u16x8*)(srow + j0);
    float v[8];
#pragma unroll
    for (int e = 0; e < 8; e++) v[e] = (j0 + e < n) ? b2f(raw[e]) : -1e30f;

    float lmax = v[0];
#pragma unroll
    for (int e = 1; e < 8; e++) lmax = fmaxf(lmax, v[e]);
    for (int o = 32; o > 0; o >>= 1) lmax = fmaxf(lmax, __shfl_xor(lmax, o, 64));
    int wid = threadIdx.x >> 6;
    if ((threadIdx.x & 63) == 0) red[wid] = lmax;
    __syncthreads();
    float Mx = fmaxf(fmaxf(red[0], red[1]), fmaxf(red[2], red[3]));

    // exp((s-Mx)/32) = exp2((s-Mx) * (1/(32 ln2)))
    const float C = 0.045112384f;
    float ev[8];
    float lsum = 0.f;
#pragma unroll
    for (int e = 0; e < 8; e++) {
        ev[e] = (j0 + e < n) ? exp2f((v[e] - Mx) * C) : 0.f;
        lsum += ev[e];
    }
    for (int o = 32; o > 0; o >>= 1) lsum += __shfl_xor(lsum, o, 64);
    if ((threadIdx.x & 63) == 0) red[4 + wid] = lsum;
    __syncthreads();
    float inv = 1.0f / (red[4] + red[5] + red[6] + red[7]);

    if (j0 < kendr) {
        u16x8 o8;
#pragma unroll
        for (int e = 0; e < 8; e++) o8[e] = f2b(ev[e] * inv);
        *(u16x8*)(prow + j0) = o8;
    }
}

// V projection (512 blocks, first so they're resident early) + paired-row
// softmax (4096 blocks). V depends only on cast; softmax only on sc.
__global__ __launch_bounds__(256, 4) void v_softmax(
    const u16* __restrict__ xb, const u16* __restrict__ wb,
    u16* __restrict__ vt,
    const u16* __restrict__ sc, u16* __restrict__ P)
{
    __shared__ __align__(16) u16 As[2 * HSZ];
    __shared__ __align__(16) u16 Bs[2 * HSZ];
    int bid = blockIdx.x;
    if (bid < 512) {
        int vb = (bid & 7) * 64 + (bid >> 3);   // XCD-chunked
        int m0 = (vb >> 3) * MT;
        int n0 = (vb & 7) * NT;
        gemm_core<1, u16>(As, Bs, xb, 1024, wb + 2048 * 1024, 1024, vt, 2048,
                          m0, n0, 0, 1024);
    } else {
        float* red = (float*)As;
        int sid = bid - 512;                    // 0..4095
        int z = sid >> 10, i = sid & 1023;
        softmax_row(sc, P, z * 2048 + (2047 - i), red);
        __syncthreads();
        softmax_row(sc, P, z * 2048 + i, red);
    }
}

// ---------------- PV: split-free triangular tiles, paired LPT order --------
// Each block computes one 128x128 out-tile with its FULL causal K =
// (m+1)*128 and stores once. Block c and c+256 land on the same CU and sum
// to a constant 17 K-units; all 512 blocks co-resident.
__global__ __launch_bounds__(256, 4) void gemm_pv(
    const u16* __restrict__ P, const u16* __restrict__ vt,
    float* __restrict__ out)
{
    __shared__ __align__(16) u16 As[2 * HSZ];
    __shared__ __align__(16) u16 Bs[2 * HSZ];
    const int bid = blockIdx.x;              // 0..511
    const int m  = (bid < 256) ? (15 - (bid >> 5)) : ((bid - 256) >> 5);
    const int nz = bid & 31;
    const int n  = nz & 7;
    const int z  = nz >> 3;
    const int m0 = m * MT;

    gemm_core<0, float>(As, Bs,
        P  + (long long)z * 2048 * 2048, 2048,
        vt + (long long)z * 1024 * 2048, 2048,
        out + (long long)z * 2097152, 1024,
        m0, n * NT, 0, m0 + MT);
}

extern "C" void kernel_launch(void* const* d_in, const int* in_sizes, int n_in,
                              void* d_out, int out_size, void* d_ws, size_t ws_size,
                              hipStream_t stream) {
    const float* x  = (const float*)d_in[0];
    const float* wq = (const float*)d_in[1];
    const float* wk = (const float*)d_in[2];
    const float* wv = (const float*)d_in[3];
    float* out = (float*)d_out;

    char* ws = (char*)d_ws;
    // layout: xb 16M | wb 6M | qk 32M | sc 32M | P 32M | vt 16M
    u16* xb = (u16*)(ws);
    u16* wb = (u16*)(ws + 16777216LL);
    u16* qk = (u16*)(ws + 23068672LL);
    u16* sc = (u16*)(ws + 56623104LL);
    u16* P  = (u16*)(ws + 90177536LL);
    u16* vt = (u16*)(ws + 123731968LL);

    // 1. casts (x + 3 weights), grid-stride
    cast_all_kernel<<<1408, 256, 0, stream>>>(x, wq, wk, wv, xb);

    // 2. QK projection: 256^2, exactly 256 blocks (1/CU, no tail)
    gemm_qk256<<<256, 512, 0, stream>>>(xb, wb, qk);

    // 3. scores: 256^2, 144 blocks (single round)
    gemm_sc256<<<144, 512, 0, stream>>>(qk, sc);

    // 4. V projection + causal softmax, one dispatch (4 blocks/CU residency)
    v_softmax<<<4608, 256, 0, stream>>>(xb, wb, vt, sc, P);

    // 5. PV: split-free triangular tiles, paired LPT ordering
    gemm_pv<<<512, 256, 0, stream>>>(P, vt, out);
}